// Round 1
// baseline (166.210 us; speedup 1.0000x reference)
//
#include <hip/hip_runtime.h>
#include <hip/hip_bf16.h>

#define DD 128
#define NCLS 10
#define CHUNK 512
#define KSTEP 32

typedef __attribute__((ext_vector_type(8))) short s16x8;
typedef __attribute__((ext_vector_type(4))) float f32x4;
typedef __attribute__((ext_vector_type(4))) unsigned int u32x4;

union FU { unsigned u[4]; s16x8 v; };

__device__ inline unsigned short f2bf(float x) {
  union { float f; unsigned u; } c; c.f = x;
  unsigned u = c.u;
  u += 0x7fffu + ((u >> 16) & 1u);   // RNE to bf16
  return (unsigned short)(u >> 16);
}

// ---------------- K1a: labels + class histogram ----------------
__global__ void k_label(const float* __restrict__ Pi, int N,
                        unsigned char* __restrict__ label, int* __restrict__ meta) {
  __shared__ int h[NCLS];
  int t = threadIdx.x;
  if (t < NCLS) h[t] = 0;
  __syncthreads();
  int n = blockIdx.x * 256 + t;
  if (n < N) {
    const float* p = Pi + (size_t)n * NCLS;
    float best = p[0]; int bj = 0;
#pragma unroll
    for (int j = 1; j < NCLS; j++) { float v = p[j]; if (v > best) { best = v; bj = j; } }
    label[n] = (unsigned char)bj;
    atomicAdd(&h[bj], 1);
  }
  __syncthreads();
  if (t < NCLS) atomicAdd(&meta[t], h[t]);
}

// ---------------- K2: prefix over padded counts, init cursors ----------------
// meta: [0..9]=counts  [10..20]=chunkstart(11)  [32..41]=cursors
__global__ void k_prefix(int* meta) {
  if (threadIdx.x == 0) {
    int cs = 0;
    meta[10] = 0;
    for (int j = 0; j < NCLS; j++) {
      int cp = (meta[j] + CHUNK - 1) / CHUNK;
      meta[32 + j] = cs * CHUNK;    // cursor = padded offset
      cs += cp;
      meta[10 + j + 1] = cs;
    }
  }
}

// ---------------- K1b: block-aggregated counting sort -> perm ----------------
__global__ void k_rank(const unsigned char* __restrict__ label, int N,
                       int* __restrict__ meta, int* __restrict__ perm) {
  __shared__ int h[NCLS];
  __shared__ int base[NCLS];
  int t = threadIdx.x;
  if (t < NCLS) h[t] = 0;
  __syncthreads();
  int n = blockIdx.x * 256 + t;
  int lj = 0, lr = 0;
  bool act = (n < N);
  if (act) { lj = label[n]; lr = atomicAdd(&h[lj], 1); }
  __syncthreads();
  if (t < NCLS) base[t] = atomicAdd(&meta[32 + t], h[t]);
  __syncthreads();
  if (act) perm[base[lj] + lr] = n;
}

// ---------------- K4: gather syrk, bf16 MFMA, per-chunk partials ----------------
__global__ __launch_bounds__(256) void k_syrk(const float* __restrict__ Z,
                                              const int* __restrict__ perm,
                                              const int* __restrict__ meta,
                                              float* __restrict__ partial) {
  __shared__ u32x4 ldsq[528];               // 16 pair-rows * 528 B = 8448 B
  char* ldsc = (char*)ldsq;
  int b = blockIdx.x;
  if (b >= meta[20]) return;                // beyond actual chunk count
  int t = threadIdx.x;
  int l = t & 63;
  int w = t >> 6;
  int g = l >> 4, m = l & 15;
  int d0 = (w >> 1) * 64, e0 = (w & 1) * 64;
  int sk2 = t >> 4;                         // staging pair-row 0..15
  int sq = t & 15;                          // staging quad base
  int rowbase = b * CHUNK;
  f32x4 acc[4][4] = {};

  for (int ks = 0; ks < CHUNK / KSTEP; ks++) {
    int r0 = rowbase + ks * KSTEP;
    int ra = perm[r0 + 2 * sk2];
    int rb = perm[r0 + 2 * sk2 + 1];
    __syncthreads();
#pragma unroll
    for (int qi = 0; qi < 2; qi++) {
      int q = sq + qi * 16;
      f32x4 va = {}, vb = {};
      if (ra >= 0) va = *(const f32x4*)(Z + (size_t)ra * DD + q * 4);
      if (rb >= 0) vb = *(const f32x4*)(Z + (size_t)rb * DD + q * 4);
      u32x4 u;
#pragma unroll
      for (int i = 0; i < 4; i++)
        u[i] = (unsigned)f2bf(va[i]) | ((unsigned)f2bf(vb[i]) << 16);
      *(u32x4*)(ldsc + sk2 * 528 + q * 16) = u;   // paired [k2][col][2] layout
    }
    __syncthreads();
    FU A[4], B[4];
    const char* fbase = ldsc + g * (4 * 528) + m * 4;
#pragma unroll
    for (int dt = 0; dt < 4; dt++) {
      const char* p = fbase + (d0 + dt * 16) * 4;
      A[dt].u[0] = *(const unsigned*)(p);
      A[dt].u[1] = *(const unsigned*)(p + 528);
      A[dt].u[2] = *(const unsigned*)(p + 1056);
      A[dt].u[3] = *(const unsigned*)(p + 1584);
    }
    if (d0 != e0) {
#pragma unroll
      for (int et = 0; et < 4; et++) {
        const char* p = fbase + (e0 + et * 16) * 4;
        B[et].u[0] = *(const unsigned*)(p);
        B[et].u[1] = *(const unsigned*)(p + 528);
        B[et].u[2] = *(const unsigned*)(p + 1056);
        B[et].u[3] = *(const unsigned*)(p + 1584);
      }
    } else {
#pragma unroll
      for (int et = 0; et < 4; et++) B[et] = A[et];
    }
#pragma unroll
    for (int dt = 0; dt < 4; dt++)
#pragma unroll
      for (int et = 0; et < 4; et++)
        acc[dt][et] = __builtin_amdgcn_mfma_f32_16x16x32_bf16(A[dt].v, B[et].v, acc[dt][et], 0, 0, 0);
  }

  float* pb = partial + (size_t)b * 16384;
#pragma unroll
  for (int dt = 0; dt < 4; dt++)
#pragma unroll
    for (int et = 0; et < 4; et++)
#pragma unroll
      for (int r = 0; r < 4; r++)
        pb[(d0 + dt * 16 + g * 4 + r) * DD + (e0 + et * 16 + m)] = acc[dt][et][r];
}

// ---------------- K5: reduce chunk partials -> M[j] ----------------
__global__ void k_reduce(const float* __restrict__ partial, const int* __restrict__ meta,
                         float* __restrict__ M) {
  int gid = blockIdx.x * 256 + threadIdx.x;   // 640 blocks
  int j = gid >> 14;
  int idx = gid & 16383;
  if (j >= NCLS) return;
  int c0 = meta[10 + j], c1 = meta[11 + j];
  float s = 0.0f;
  for (int c = c0; c < c1; c++) s += partial[(size_t)c * 16384 + idx];
  M[(size_t)j * 16384 + idx] = s;
}

// ---------------- K5b: S = I + cfac * sum_j M[j] ----------------
__global__ void k_makeS(const float* __restrict__ M, float* __restrict__ S, float cfac) {
  int idx = blockIdx.x * 256 + threadIdx.x;   // 64 blocks
  float s = 0.0f;
#pragma unroll
  for (int j = 0; j < NCLS; j++) s += M[(size_t)j * 16384 + idx];
  int d2 = idx >> 7, e2 = idx & 127;
  S[idx] = (d2 == e2 ? 1.0f : 0.0f) + cfac * s;
}

// ---------------- K6: blocked Cholesky (128x128) + logdet ----------------
#define SM(i, c) Ssh[(((i) << 7)) | (((unsigned)(c)) ^ ((unsigned)(i) & 31u))]
__global__ __launch_bounds__(512) void k_chol(const float* __restrict__ Sg, float* __restrict__ scal) {
  __shared__ float Ssh[16384];
  int t = threadIdx.x;
  for (int idx = t; idx < 16384; idx += 512) {
    int i = idx >> 7, c = idx & 127;
    SM(i, c) = Sg[idx];
  }
  __syncthreads();
  for (int p = 0; p < 8; p++) {
    int pc = p * 16;
    if (t < 16) {                       // panel factor, wave0 lanes 0..15, registers+shfl
      float row[16];
#pragma unroll
      for (int c = 0; c < 16; c++) row[c] = SM(pc + t, pc + c);
#pragma unroll
      for (int kk = 0; kk < 16; kk++) {
        float piv = __shfl(row[kk], kk);
        float s = sqrtf(piv);
        float inv = 1.0f / s;
        if (t == kk) row[kk] = s;
        if (t > kk) row[kk] *= inv;
#pragma unroll
        for (int c = kk + 1; c < 16; c++) {
          float ljk = __shfl(row[kk], c);
          if (t >= c) row[c] -= row[kk] * ljk;
        }
      }
#pragma unroll
      for (int c = 0; c < 16; c++) if (c <= t) SM(pc + t, pc + c) = row[c];
    }
    __syncthreads();
    int s0 = pc + 16;
    if (s0 < 128) {
      if (t < 128 - s0) {               // triangular solve for panel columns
        int i = s0 + t;
        float r[16];
#pragma unroll
        for (int c = 0; c < 16; c++) r[c] = SM(i, pc + c);
#pragma unroll
        for (int c = 0; c < 16; c++) {
          float a = r[c];
          for (int m2 = 0; m2 < c; m2++) a -= r[m2] * SM(pc + c, pc + m2);
          r[c] = a / SM(pc + c, pc + c);
        }
#pragma unroll
        for (int c = 0; c < 16; c++) SM(i, pc + c) = r[c];
      }
      __syncthreads();
      int msz = 128 - s0;
      int tpd = msz >> 3;
      for (int tile = t; tile < tpd * tpd; tile += 512) {   // rank-16 trailing, 8x8 reg tiles
        int i0 = s0 + (tile / tpd) * 8, j0 = s0 + (tile % tpd) * 8;
        float a[8][8];
#pragma unroll
        for (int r = 0; r < 8; r++)
#pragma unroll
          for (int c = 0; c < 8; c++) a[r][c] = SM(i0 + r, j0 + c);
        for (int m2 = 0; m2 < 16; m2++) {
          float ri[8], rj[8];
#pragma unroll
          for (int r = 0; r < 8; r++) ri[r] = SM(i0 + r, pc + m2);
#pragma unroll
          for (int c = 0; c < 8; c++) rj[c] = SM(j0 + c, pc + m2);
#pragma unroll
          for (int r = 0; r < 8; r++)
#pragma unroll
            for (int c = 0; c < 8; c++) a[r][c] -= ri[r] * rj[c];
        }
#pragma unroll
        for (int r = 0; r < 8; r++)
#pragma unroll
          for (int c = 0; c < 8; c++) SM(i0 + r, j0 + c) = a[r][c];
      }
      __syncthreads();
    }
  }
  __syncthreads();
  float v = 0.0f;
  if (t < 128) v = logf(SM(t, t));
  __syncthreads();
  if (t < 128) Ssh[t] = v;
  __syncthreads();
  if (t == 0) {
    float s = 0.0f;
    for (int i = 0; i < 128; i++) s += Ssh[i];
    scal[0] = s;                       // loss_R = 0.5*logdet = sum log diag(L)
  }
}

// ---------------- K7a: column norms of Us + loss_Rc ----------------
__global__ void k_colnorm(const float* __restrict__ Us, const int* __restrict__ meta,
                          float* __restrict__ scal, float nf) {
  int j = blockIdx.x, e = threadIdx.x;     // 10 blocks x 128 threads
  const float* U = Us + (size_t)j * 16384;
  float acc = 0.0f;
  for (int d2 = 0; d2 < 128; d2++) { float v = U[d2 * 128 + e]; acc += v * v; }
  float trj = (float)meta[j];
  float term = log1pf((128.0f / (trj * 0.5f)) * acc);
#pragma unroll
  for (int o = 32; o; o >>= 1) term += __shfl_down(term, o);
  __shared__ float ws2[2];
  if ((e & 63) == 0) ws2[e >> 6] = term;
  __syncthreads();
  if (e == 0) atomicAdd(&scal[1], (trj / (2.0f * nf)) * (ws2[0] + ws2[1]));
}

// ---------------- K7b: sum (M - Us Us^T)^2 ----------------
__global__ __launch_bounds__(256) void k_reg(const float* __restrict__ Us,
                                             const float* __restrict__ Mg,
                                             float* __restrict__ scal) {
  __shared__ float ldsA[16][132];
  __shared__ float ldsB[16][132];
  __shared__ float wsum[4];
  int bid = blockIdx.x;                 // 640 = 10 * 64
  int j = bid >> 6, tile = bid & 63;
  int dr = (tile >> 3) << 4, er = (tile & 7) << 4;
  int t = threadIdx.x;
  int r = t >> 4, cb = t & 15;
  const float* src = Us + (size_t)j * 16384;
  {
    f32x4 a0 = *(const f32x4*)(src + (dr + r) * 128 + cb * 8);
    f32x4 a1 = *(const f32x4*)(src + (dr + r) * 128 + cb * 8 + 4);
    *(f32x4*)(&ldsA[r][cb * 8]) = a0;
    *(f32x4*)(&ldsA[r][cb * 8 + 4]) = a1;
    f32x4 b0 = *(const f32x4*)(src + (er + r) * 128 + cb * 8);
    f32x4 b1 = *(const f32x4*)(src + (er + r) * 128 + cb * 8 + 4);
    *(f32x4*)(&ldsB[r][cb * 8]) = b0;
    *(f32x4*)(&ldsB[r][cb * 8 + 4]) = b1;
  }
  __syncthreads();
  int dd = t >> 4, ee = t & 15;
  float acc = 0.0f;
#pragma unroll 8
  for (int k = 0; k < 128; k++) acc += ldsA[dd][k] * ldsB[ee][k];
  float mval = Mg[(size_t)j * 16384 + (dr + dd) * 128 + (er + ee)];
  float v = mval - acc;
  float sq = v * v;
#pragma unroll
  for (int o = 32; o; o >>= 1) sq += __shfl_down(sq, o);
  if ((t & 63) == 0) wsum[t >> 6] = sq;
  __syncthreads();
  if (t == 0) atomicAdd(&scal[2], wsum[0] + wsum[1] + wsum[2] + wsum[3]);
}

// ---------------- K8: finalize ----------------
__global__ void k_final(const float* __restrict__ scal, float* __restrict__ out) {
  if (threadIdx.x == 0) {
    float R = scal[0], Rc = scal[1], reg = 0.5f * scal[2];   // MU = 1
    out[0] = -(R - Rc - reg);
    out[1] = R;
    out[2] = Rc;
    out[3] = reg;
  }
}

extern "C" void kernel_launch(void* const* d_in, const int* in_sizes, int n_in,
                              void* d_out, int out_size, void* d_ws, size_t ws_size,
                              hipStream_t stream) {
  const float* Z = (const float*)d_in[0];
  const float* Pi = (const float*)d_in[1];
  const float* Us = (const float*)d_in[2];
  float* out = (float*)d_out;
  int N = in_sizes[0] / DD;
  int NPAD = N + NCLS * CHUNK;
  int MC = (N + CHUNK - 1) / CHUNK + NCLS;

  char* ws = (char*)d_ws;
  int* meta = (int*)ws;                       // 64 ints
  float* scal = (float*)(ws + 256);           // 16 floats
  int* perm = (int*)(ws + 512);
  size_t off = 512 + (size_t)NPAD * 4;
  off = (off + 511) & ~511ull;
  unsigned char* label = (unsigned char*)(ws + off);
  off += (size_t)N; off = (off + 511) & ~511ull;
  float* M = (float*)(ws + off); off += (size_t)NCLS * 16384 * 4;
  float* S = (float*)(ws + off); off += (size_t)16384 * 4;
  float* partial = (float*)(ws + off); off += (size_t)MC * 16384 * 4;

  hipMemsetAsync(ws, 0, 512, stream);                          // counts/cursors/scalars = 0
  hipMemsetAsync(perm, 0xFF, (size_t)NPAD * 4, stream);        // perm = -1 (padding rows)

  int nb = (N + 255) / 256;
  k_label<<<nb, 256, 0, stream>>>(Pi, N, label, meta);
  k_prefix<<<1, 32, 0, stream>>>(meta);
  k_rank<<<nb, 256, 0, stream>>>(label, N, meta, perm);
  k_syrk<<<MC, 256, 0, stream>>>(Z, perm, meta, partial);
  k_reduce<<<640, 256, 0, stream>>>(partial, meta, M);
  k_makeS<<<64, 256, 0, stream>>>(M, S, (float)DD / ((float)N * 0.5f));
  k_chol<<<1, 512, 0, stream>>>(S, scal);
  k_colnorm<<<NCLS, 128, 0, stream>>>(Us, meta, scal, (float)N);
  k_reg<<<640, 256, 0, stream>>>(Us, M, scal);
  k_final<<<1, 64, 0, stream>>>(scal, out);
}

// Round 2
// 102.523 us; speedup vs baseline: 1.6212x; 1.6212x over previous
//
#include <hip/hip_runtime.h>
#include <hip/hip_bf16.h>

#define DD 128
#define NCLS 10
#define CHUNK 512
#define KSTEP 32

typedef __attribute__((ext_vector_type(8))) short s16x8;
typedef __attribute__((ext_vector_type(4))) float f32x4;
typedef __attribute__((ext_vector_type(4))) unsigned int u32x4;
typedef __attribute__((ext_vector_type(4))) unsigned short u16x4;

union FU { unsigned u[4]; s16x8 v; };

__device__ inline unsigned short f2bf(float x) {
  union { float f; unsigned u; } c; c.f = x;
  unsigned u = c.u;
  u += 0x7fffu + ((u >> 16) & 1u);   // RNE to bf16
  return (unsigned short)(u >> 16);
}

// ---------------- K1a: labels + class histogram ----------------
__global__ void k_label(const float* __restrict__ Pi, int N,
                        unsigned char* __restrict__ label, int* __restrict__ meta) {
  __shared__ int h[NCLS];
  int t = threadIdx.x;
  if (t < NCLS) h[t] = 0;
  __syncthreads();
  int n = blockIdx.x * 256 + t;
  if (n < N) {
    const float* p = Pi + (size_t)n * NCLS;
    float best = p[0]; int bj = 0;
#pragma unroll
    for (int j = 1; j < NCLS; j++) { float v = p[j]; if (v > best) { best = v; bj = j; } }
    label[n] = (unsigned char)bj;
    atomicAdd(&h[bj], 1);
  }
  __syncthreads();
  if (t < NCLS) atomicAdd(&meta[t], h[t]);
}

// ---------------- K2: prefix over padded counts, init cursors ----------------
// meta: [0..9]=counts  [10..20]=chunkstart(11)  [32..41]=cursors
__global__ void k_prefix(int* meta) {
  if (threadIdx.x == 0) {
    int cs = 0;
    meta[10] = 0;
    for (int j = 0; j < NCLS; j++) {
      int cp = (meta[j] + CHUNK - 1) / CHUNK;
      meta[32 + j] = cs * CHUNK;    // cursor = padded offset
      cs += cp;
      meta[10 + j + 1] = cs;
    }
  }
}

// ---------------- K1b: block-aggregated counting sort -> perm ----------------
__global__ void k_rank(const unsigned char* __restrict__ label, int N,
                       int* __restrict__ meta, int* __restrict__ perm) {
  __shared__ int h[NCLS];
  __shared__ int base[NCLS];
  int t = threadIdx.x;
  if (t < NCLS) h[t] = 0;
  __syncthreads();
  int n = blockIdx.x * 256 + t;
  int lj = 0, lr = 0;
  bool act = (n < N);
  if (act) { lj = label[n]; lr = atomicAdd(&h[lj], 1); }
  __syncthreads();
  if (t < NCLS) base[t] = atomicAdd(&meta[32 + t], h[t]);
  __syncthreads();
  if (act) perm[base[lj] + lr] = n;
}

// ---------------- K4: gather syrk, bf16 MFMA, per-chunk partials ----------------
__global__ __launch_bounds__(256) void k_syrk(const float* __restrict__ Z,
                                              const int* __restrict__ perm,
                                              const int* __restrict__ meta,
                                              float* __restrict__ partial) {
  __shared__ u32x4 ldsq[528];               // 16 pair-rows * 528 B = 8448 B
  char* ldsc = (char*)ldsq;
  int b = blockIdx.x;
  if (b >= meta[20]) return;                // beyond actual chunk count
  int t = threadIdx.x;
  int l = t & 63;
  int w = t >> 6;
  int g = l >> 4, m = l & 15;
  int d0 = (w >> 1) * 64, e0 = (w & 1) * 64;
  int sk2 = t >> 4;                         // staging pair-row 0..15
  int sq = t & 15;                          // staging quad base
  int rowbase = b * CHUNK;
  f32x4 acc[4][4] = {};

  for (int ks = 0; ks < CHUNK / KSTEP; ks++) {
    int r0 = rowbase + ks * KSTEP;
    int ra = perm[r0 + 2 * sk2];
    int rb = perm[r0 + 2 * sk2 + 1];
    __syncthreads();
#pragma unroll
    for (int qi = 0; qi < 2; qi++) {
      int q = sq + qi * 16;
      f32x4 va = {}, vb = {};
      if (ra >= 0) va = *(const f32x4*)(Z + (size_t)ra * DD + q * 4);
      if (rb >= 0) vb = *(const f32x4*)(Z + (size_t)rb * DD + q * 4);
      u32x4 u;
#pragma unroll
      for (int i = 0; i < 4; i++)
        u[i] = (unsigned)f2bf(va[i]) | ((unsigned)f2bf(vb[i]) << 16);
      *(u32x4*)(ldsc + sk2 * 528 + q * 16) = u;   // paired [k2][col][2] layout
    }
    __syncthreads();
    FU A[4], B[4];
    const char* fbase = ldsc + g * (4 * 528) + m * 4;
#pragma unroll
    for (int dt = 0; dt < 4; dt++) {
      const char* p = fbase + (d0 + dt * 16) * 4;
      A[dt].u[0] = *(const unsigned*)(p);
      A[dt].u[1] = *(const unsigned*)(p + 528);
      A[dt].u[2] = *(const unsigned*)(p + 1056);
      A[dt].u[3] = *(const unsigned*)(p + 1584);
    }
    if (d0 != e0) {
#pragma unroll
      for (int et = 0; et < 4; et++) {
        const char* p = fbase + (e0 + et * 16) * 4;
        B[et].u[0] = *(const unsigned*)(p);
        B[et].u[1] = *(const unsigned*)(p + 528);
        B[et].u[2] = *(const unsigned*)(p + 1056);
        B[et].u[3] = *(const unsigned*)(p + 1584);
      }
    } else {
#pragma unroll
      for (int et = 0; et < 4; et++) B[et] = A[et];
    }
#pragma unroll
    for (int dt = 0; dt < 4; dt++)
#pragma unroll
      for (int et = 0; et < 4; et++)
        acc[dt][et] = __builtin_amdgcn_mfma_f32_16x16x32_bf16(A[dt].v, B[et].v, acc[dt][et], 0, 0, 0);
  }

  float* pb = partial + (size_t)b * 16384;
#pragma unroll
  for (int dt = 0; dt < 4; dt++)
#pragma unroll
    for (int et = 0; et < 4; et++)
#pragma unroll
      for (int r = 0; r < 4; r++)
        pb[(d0 + dt * 16 + g * 4 + r) * DD + (e0 + et * 16 + m)] = acc[dt][et][r];
}

// ---------------- K5: reduce chunk partials -> M[j] ----------------
__global__ void k_reduce(const float* __restrict__ partial, const int* __restrict__ meta,
                         float* __restrict__ M) {
  int gid = blockIdx.x * 256 + threadIdx.x;   // 640 blocks
  int j = gid >> 14;
  int idx = gid & 16383;
  if (j >= NCLS) return;
  int c0 = meta[10 + j], c1 = meta[11 + j];
  float s = 0.0f;
  for (int c = c0; c < c1; c++) s += partial[(size_t)c * 16384 + idx];
  M[(size_t)j * 16384 + idx] = s;
}

// ---------------- K5b: Gram = sum_j M[j]; tr(Gram) -> scal[0] ----------------
__global__ void k_gram(const float* __restrict__ M, float* __restrict__ Gram,
                       float* __restrict__ scal) {
  int idx = blockIdx.x * 256 + threadIdx.x;   // 64 blocks
  float s = 0.0f;
#pragma unroll
  for (int j = 0; j < NCLS; j++) s += M[(size_t)j * 16384 + idx];
  Gram[idx] = s;
  if ((idx >> 7) == (idx & 127)) atomicAdd(&scal[0], s);
}

// ---------------- K6: makeE (+t1,t2) fused with colnorm ----------------
// blocks 0..63: E = (cf/c)*Gram + (1/c-1)*I ; Ebf ; t1=tr(E), t2=sum E*E
// blocks 64..73: colnorm for class j=b-64
__global__ __launch_bounds__(256) void k_makeE_cn(const float* __restrict__ Gram,
                                                  const float* __restrict__ Us,
                                                  const int* __restrict__ meta,
                                                  float* __restrict__ scal,
                                                  float* __restrict__ E,
                                                  unsigned short* __restrict__ Ebf,
                                                  float cf, float nf) {
  __shared__ __align__(16) char pool[1024];
  float* red = (float*)pool;
  int b = blockIdx.x, t = threadIdx.x;
  if (b < 64) {
    int idx = b * 256 + t;
    float c = 1.0f + cf * scal[0] * (1.0f / 128.0f);
    float rc = 1.0f / c;
    int dg = ((idx >> 7) == (idx & 127)) ? 1 : 0;
    float e = (cf * rc) * Gram[idx] + (dg ? (rc - 1.0f) : 0.0f);
    E[idx] = e;
    Ebf[idx] = f2bf(e);
    float p1 = dg ? e : 0.0f;
    float p2 = e * e;
#pragma unroll
    for (int o = 32; o; o >>= 1) { p1 += __shfl_down(p1, o); p2 += __shfl_down(p2, o); }
    if ((t & 63) == 0) { red[t >> 6] = p1; red[4 + (t >> 6)] = p2; }
    __syncthreads();
    if (t == 0) {
      atomicAdd(&scal[3], red[0] + red[1] + red[2] + red[3]);
      atomicAdd(&scal[4], red[4] + red[5] + red[6] + red[7]);
    }
  } else {
    int j = b - 64;
    const float* U = Us + (size_t)j * 16384;
    int e = t & 127, half = t >> 7;
    float* cs = (float*)pool;            // 128 floats
    float* red2 = (float*)(pool + 512);
    float acc = 0.0f;
    int d0 = half * 64;
    for (int d2 = d0; d2 < d0 + 64; d2++) { float v = U[d2 * 128 + e]; acc += v * v; }
    if (half == 0) cs[e] = acc;
    __syncthreads();
    float trj = (float)meta[j];
    float term = 0.0f;
    if (half == 1) {
      float tot = cs[e] + acc;
      term = log1pf((256.0f / trj) * tot);
    }
#pragma unroll
    for (int o = 32; o; o >>= 1) term += __shfl_down(term, o);
    if ((t & 63) == 0) red2[t >> 6] = term;
    __syncthreads();
    if (t == 0) atomicAdd(&scal[1], (trj / (2.0f * nf)) * (red2[2] + red2[3]));
  }
}

// ---------------- mm tail: P = X^T Y (symmetric operands), 128x128, one block ----
// taccA = sum P .* Tdot ; taccB = sum P .* P ; optional stores of P (f32/bf16)
__device__ __forceinline__ void mm_tail(const unsigned short* __restrict__ Xbf,
                                        const unsigned short* __restrict__ Ybf,
                                        float* __restrict__ Pf,
                                        unsigned short* __restrict__ Pbf,
                                        const float* __restrict__ Tdot,
                                        char* ldsX, char* ldsY, int t,
                                        float& tA, float& tB) {
  int l = t & 63, w = t >> 6;
  int g = l >> 4, m = l & 15;
  int d0 = (w >> 1) * 64, e0 = (w & 1) * 64;
  int sk2 = t >> 4, sq = t & 15;
  bool same = (Xbf == Ybf);
  f32x4 acc[4][4] = {};
  for (int ks = 0; ks < 4; ks++) {
    int k0 = ks * 32 + 2 * sk2;
    __syncthreads();
#pragma unroll
    for (int qi = 0; qi < 2; qi++) {
      int q = sq + qi * 16;
      u16x4 a = *(const u16x4*)(Xbf + k0 * 128 + q * 4);
      u16x4 bb = *(const u16x4*)(Xbf + (k0 + 1) * 128 + q * 4);
      u32x4 u;
#pragma unroll
      for (int i = 0; i < 4; i++) u[i] = (unsigned)a[i] | ((unsigned)bb[i] << 16);
      *(u32x4*)(ldsX + sk2 * 528 + q * 16) = u;
      if (!same) {
        u16x4 c0 = *(const u16x4*)(Ybf + k0 * 128 + q * 4);
        u16x4 d1 = *(const u16x4*)(Ybf + (k0 + 1) * 128 + q * 4);
        u32x4 v;
#pragma unroll
        for (int i = 0; i < 4; i++) v[i] = (unsigned)c0[i] | ((unsigned)d1[i] << 16);
        *(u32x4*)(ldsY + sk2 * 528 + q * 16) = v;
      }
    }
    __syncthreads();
    const char* ldsB = same ? ldsX : ldsY;
    FU A[4], B[4];
    const char* fa = ldsX + g * (4 * 528) + m * 4;
    const char* fb = ldsB + g * (4 * 528) + m * 4;
#pragma unroll
    for (int dt = 0; dt < 4; dt++) {
      const char* p = fa + (d0 + dt * 16) * 4;
      A[dt].u[0] = *(const unsigned*)(p);
      A[dt].u[1] = *(const unsigned*)(p + 528);
      A[dt].u[2] = *(const unsigned*)(p + 1056);
      A[dt].u[3] = *(const unsigned*)(p + 1584);
      const char* p2 = fb + (e0 + dt * 16) * 4;
      B[dt].u[0] = *(const unsigned*)(p2);
      B[dt].u[1] = *(const unsigned*)(p2 + 528);
      B[dt].u[2] = *(const unsigned*)(p2 + 1056);
      B[dt].u[3] = *(const unsigned*)(p2 + 1584);
    }
#pragma unroll
    for (int dt = 0; dt < 4; dt++)
#pragma unroll
      for (int et = 0; et < 4; et++)
        acc[dt][et] = __builtin_amdgcn_mfma_f32_16x16x32_bf16(A[dt].v, B[et].v, acc[dt][et], 0, 0, 0);
  }
  tA = 0.0f; tB = 0.0f;
#pragma unroll
  for (int dt = 0; dt < 4; dt++)
#pragma unroll
    for (int et = 0; et < 4; et++)
#pragma unroll
      for (int r = 0; r < 4; r++) {
        int idx = (d0 + dt * 16 + g * 4 + r) * 128 + (e0 + et * 16 + m);
        float p = acc[dt][et][r];
        if (Pf) Pf[idx] = p;
        if (Pbf) Pbf[idx] = f2bf(p);
        tA += p * Tdot[idx];
        tB += p * p;
      }
}

// ---------------- K7: E2 = E*E (+t3,t4) on block 0; k_reg on blocks 1..640 ----
__global__ __launch_bounds__(256) void k_e2_reg(const unsigned short* __restrict__ Ebf,
                                                const float* __restrict__ E,
                                                float* __restrict__ E2f,
                                                unsigned short* __restrict__ E2bf,
                                                const float* __restrict__ Us,
                                                const float* __restrict__ Mg,
                                                float* __restrict__ scal) {
  __shared__ __align__(16) char pool[17024];
  int b = blockIdx.x, t = threadIdx.x;
  if (b == 0) {
    float tA, tB;
    mm_tail(Ebf, Ebf, E2f, E2bf, E, pool, pool, t, tA, tB);
    float* red = (float*)(pool + 16896);
#pragma unroll
    for (int o = 32; o; o >>= 1) { tA += __shfl_down(tA, o); tB += __shfl_down(tB, o); }
    __syncthreads();
    if ((t & 63) == 0) { red[t >> 6] = tA; red[4 + (t >> 6)] = tB; }
    __syncthreads();
    if (t == 0) {
      atomicAdd(&scal[5], red[0] + red[1] + red[2] + red[3]);
      atomicAdd(&scal[6], red[4] + red[5] + red[6] + red[7]);
    }
  } else {
    int bid = b - 1;                 // 640 = 10 * 64
    int j = bid >> 6, tile = bid & 63;
    int dr = (tile >> 3) << 4, er = (tile & 7) << 4;
    float (*ldsA)[132] = (float(*)[132])pool;
    float (*ldsB)[132] = (float(*)[132])(pool + 8448);
    float* wsum = (float*)(pool + 16896);
    int r = t >> 4, cb = t & 15;
    const float* src = Us + (size_t)j * 16384;
    {
      f32x4 a0 = *(const f32x4*)(src + (dr + r) * 128 + cb * 8);
      f32x4 a1 = *(const f32x4*)(src + (dr + r) * 128 + cb * 8 + 4);
      *(f32x4*)(&ldsA[r][cb * 8]) = a0;
      *(f32x4*)(&ldsA[r][cb * 8 + 4]) = a1;
      f32x4 b0 = *(const f32x4*)(src + (er + r) * 128 + cb * 8);
      f32x4 b1 = *(const f32x4*)(src + (er + r) * 128 + cb * 8 + 4);
      *(f32x4*)(&ldsB[r][cb * 8]) = b0;
      *(f32x4*)(&ldsB[r][cb * 8 + 4]) = b1;
    }
    __syncthreads();
    int dd = t >> 4, ee = t & 15;
    float acc = 0.0f;
#pragma unroll 8
    for (int k = 0; k < 128; k++) acc += ldsA[dd][k] * ldsB[ee][k];
    float mval = Mg[(size_t)j * 16384 + (dr + dd) * 128 + (er + ee)];
    float v = mval - acc;
    float sq = v * v;
#pragma unroll
    for (int o = 32; o; o >>= 1) sq += __shfl_down(sq, o);
    if ((t & 63) == 0) wsum[t >> 6] = sq;
    __syncthreads();
    if (t == 0) atomicAdd(&scal[2], wsum[0] + wsum[1] + wsum[2] + wsum[3]);
  }
}

// ---------------- K8: E3 = E*E2 traces (t5,t6) + finalize ----------------
__global__ __launch_bounds__(256) void k_e3_final(const unsigned short* __restrict__ Ebf,
                                                  const unsigned short* __restrict__ E2bf,
                                                  const float* __restrict__ E2f,
                                                  const float* __restrict__ scal,
                                                  float* __restrict__ out, float cf) {
  __shared__ __align__(16) char pool[17024];
  int t = threadIdx.x;
  float tA, tB;
  mm_tail(Ebf, E2bf, (float*)nullptr, (unsigned short*)nullptr, E2f,
          pool, pool + 8448, t, tA, tB);
  float* red = (float*)(pool + 16896);
#pragma unroll
  for (int o = 32; o; o >>= 1) { tA += __shfl_down(tA, o); tB += __shfl_down(tB, o); }
  __syncthreads();
  if ((t & 63) == 0) { red[t >> 6] = tA; red[4 + (t >> 6)] = tB; }
  __syncthreads();
  if (t == 0) {
    float t5 = red[0] + red[1] + red[2] + red[3];
    float t6 = red[4] + red[5] + red[6] + red[7];
    float c = 1.0f + cf * scal[0] * (1.0f / 128.0f);
    float t1 = scal[3], t2 = scal[4], t3 = scal[5], t4 = scal[6];
    float logdet = 128.0f * logf(c) + t1 - 0.5f * t2 + t3 * (1.0f / 3.0f)
                 - 0.25f * t4 + t5 * 0.2f - t6 * (1.0f / 6.0f);
    float R = 0.5f * logdet;
    float Rc = scal[1];
    float reg = 0.5f * scal[2];
    out[0] = -(R - Rc - reg);
    out[1] = R;
    out[2] = Rc;
    out[3] = reg;
  }
}

extern "C" void kernel_launch(void* const* d_in, const int* in_sizes, int n_in,
                              void* d_out, int out_size, void* d_ws, size_t ws_size,
                              hipStream_t stream) {
  const float* Z = (const float*)d_in[0];
  const float* Pi = (const float*)d_in[1];
  const float* Us = (const float*)d_in[2];
  float* out = (float*)d_out;
  int N = in_sizes[0] / DD;
  int NPAD = N + NCLS * CHUNK;
  int MC = (N + CHUNK - 1) / CHUNK + NCLS;
  float cf = (float)DD / ((float)N * 0.5f);   // d/(n*eps)

  char* ws = (char*)d_ws;
  int* meta = (int*)ws;                       // 64 ints
  float* scal = (float*)(ws + 256);           // 16 floats
  int* perm = (int*)(ws + 512);
  size_t off = 512 + (size_t)NPAD * 4;
  off = (off + 511) & ~511ull;
  unsigned char* label = (unsigned char*)(ws + off);
  off += (size_t)N; off = (off + 511) & ~511ull;
  float* M = (float*)(ws + off); off += (size_t)NCLS * 16384 * 4;
  float* Gram = (float*)(ws + off); off += (size_t)16384 * 4;
  float* E = (float*)(ws + off); off += (size_t)16384 * 4;
  float* E2f = (float*)(ws + off); off += (size_t)16384 * 4;
  unsigned short* Ebf = (unsigned short*)(ws + off); off += (size_t)16384 * 2;
  unsigned short* E2bf = (unsigned short*)(ws + off); off += (size_t)16384 * 2;
  off = (off + 511) & ~511ull;
  float* partial = (float*)(ws + off); off += (size_t)MC * 16384 * 4;

  hipMemsetAsync(ws, 0, 512, stream);                          // counts/cursors/scalars = 0
  hipMemsetAsync(perm, 0xFF, (size_t)NPAD * 4, stream);        // perm = -1 (padding rows)

  int nb = (N + 255) / 256;
  k_label<<<nb, 256, 0, stream>>>(Pi, N, label, meta);
  k_prefix<<<1, 32, 0, stream>>>(meta);
  k_rank<<<nb, 256, 0, stream>>>(label, N, meta, perm);
  k_syrk<<<MC, 256, 0, stream>>>(Z, perm, meta, partial);
  k_reduce<<<640, 256, 0, stream>>>(partial, meta, M);
  k_gram<<<64, 256, 0, stream>>>(M, Gram, scal);
  k_makeE_cn<<<74, 256, 0, stream>>>(Gram, Us, meta, scal, E, Ebf, cf, (float)N);
  k_e2_reg<<<641, 256, 0, stream>>>(Ebf, E, E2f, E2bf, Us, M, scal);
  k_e3_final<<<1, 256, 0, stream>>>(Ebf, E2bf, E2f, scal, out, cf);
}